// Round 3
// baseline (263.245 us; speedup 1.0000x reference)
//
#include <hip/hip_runtime.h>

// DeformUnfold R2: channel-innermost gathers.
// Pass 1: transpose x[B][C][H*W] -> xT[B][H*W][C]  (in d_ws)
// Pass 2: one wave-lane-group per (4 sp x 16 ch-quads); each bilinear corner
//         is a fully-coalesced 256B read of all 64 channels of one pixel.
// Fallback to the R1 scatter-gather kernel if ws_size is too small.

constexpr int Bc = 8;
constexpr int Cc = 64;
constexpr int Hc = 128;
constexpr int Wc = 128;
constexpr int Kc = 9;
constexpr int HWc = Hc * Wc;          // 16384

// ---------------- Pass 1: CHW -> HWC transpose ----------------
__global__ __launch_bounds__(256) void transpose_chw_hwc(
    const float* __restrict__ x, float* __restrict__ xT)
{
    __shared__ float tile[64][65];     // [px][ch], pad to kill bank conflicts
    int bid    = blockIdx.x;
    int b      = bid >> 8;             // 256 px-tiles of 64 per batch
    int pxbase = (bid & 255) << 6;
    int lane   = threadIdx.x & 63;     // px within tile (read) / ch (write)
    int grp    = threadIdx.x >> 6;     // 0..3

    const float* xb = x + (size_t)b * Cc * HWc;
#pragma unroll
    for (int r = 0; r < 16; ++r) {
        int c = r * 4 + grp;
        tile[lane][c] = xb[(size_t)c * HWc + pxbase + lane];
    }
    __syncthreads();
    float* ob = xT + ((size_t)b * HWc + pxbase) * Cc;
#pragma unroll
    for (int r = 0; r < 16; ++r) {
        int px = r * 4 + grp;
        ob[(size_t)px * Cc + lane] = tile[px][lane];
    }
}

// ---------------- Pass 2: main deform-unfold ----------------
__global__ __launch_bounds__(256) void deform_main(
    const float* __restrict__ xT,
    const float* __restrict__ offset,
    float* __restrict__ out)
{
    int bid    = blockIdx.x;
    int b      = bid >> 8;             // 256 sp-tiles of 64 per batch
    int spbase = (bid & 255) << 6;
    int t      = threadIdx.x;
    int wave   = t >> 6;               // 0..3, each wave owns 16 sp
    int lane   = t & 63;
    int sp_sub = lane >> 4;            // 0..3
    int thc    = lane & 15;            // channel-quad id; ch = 4*thc..4*thc+3

    int ho     = spbase >> 7;          // tile lies within one output row
    int wobase = spbase & 127;

    const float* offb = offset + (size_t)b * (2 * Kc) * HWc;
    const float* xTb  = xT + (size_t)b * HWc * Cc;
    float* outb       = out + ((size_t)b * Cc + (size_t)thc * 4) * Kc * (size_t)HWc;

#pragma unroll 1
    for (int k = 0; k < Kc; ++k) {
        float base_y = (float)(k / 3 + ho - 1);
        float kxof   = (float)(k % 3 - 1);
        const float* offyp = offb + (size_t)(2 * k) * HWc;
        const float* offxp = offyp + HWc;
#pragma unroll
        for (int spq = 0; spq < 4; ++spq) {
            int loc = wave * 16 + spq * 4 + sp_sub;
            int sp  = spbase + loc;
            int wo  = wobase + loc;

            float py = base_y + offyp[sp];
            float px = (float)wo + kxof + offxp[sp];

            float y0f = floorf(py), x0f = floorf(px);
            float ly = py - y0f, lx = px - x0f;
            float hy = 1.0f - ly, hx = 1.0f - lx;

            int y0 = (int)y0f, x0 = (int)x0f;
            int y1 = y0 + 1,   x1 = x0 + 1;

            bool vy0 = (unsigned)y0 < (unsigned)Hc;
            bool vy1 = (unsigned)y1 < (unsigned)Hc;
            bool vx0 = (unsigned)x0 < (unsigned)Wc;
            bool vx1 = (unsigned)x1 < (unsigned)Wc;

            float w00 = hy * hx * ((vy0 & vx0) ? 1.0f : 0.0f);
            float w01 = hy * lx * ((vy0 & vx1) ? 1.0f : 0.0f);
            float w10 = ly * hx * ((vy1 & vx0) ? 1.0f : 0.0f);
            float w11 = ly * lx * ((vy1 & vx1) ? 1.0f : 0.0f);

            int y0c = min(max(y0, 0), Hc - 1);
            int y1c = min(max(y1, 0), Hc - 1);
            int x0c = min(max(x0, 0), Wc - 1);
            int x1c = min(max(x1, 0), Wc - 1);

            int p00 = (y0c << 7) + x0c;
            int p01 = (y0c << 7) + x1c;
            int p10 = (y1c << 7) + x0c;
            int p11 = (y1c << 7) + x1c;

            // 4 fully-coalesced corner loads: 64 ch x 4B = 256B per pixel
            const float4 c00 = *(const float4*)(xTb + ((size_t)p00 << 6) + thc * 4);
            const float4 c01 = *(const float4*)(xTb + ((size_t)p01 << 6) + thc * 4);
            const float4 c10 = *(const float4*)(xTb + ((size_t)p10 << 6) + thc * 4);
            const float4 c11 = *(const float4*)(xTb + ((size_t)p11 << 6) + thc * 4);

            float4 v;
            v.x = w00 * c00.x + w01 * c01.x + w10 * c10.x + w11 * c11.x;
            v.y = w00 * c00.y + w01 * c01.y + w10 * c10.y + w11 * c11.y;
            v.z = w00 * c00.z + w01 * c01.z + w10 * c10.z + w11 * c11.z;
            v.w = w00 * c00.w + w01 * c01.w + w10 * c10.w + w11 * c11.w;

            // out[((b*64 + 4*thc + j)*9 + k)*HW + sp], j = 0..3
            float* ob = outb + (size_t)k * HWc + sp;
            ob[0]                     = v.x;
            ob[(size_t)Kc * HWc]      = v.y;
            ob[(size_t)2 * Kc * HWc]  = v.z;
            ob[(size_t)3 * Kc * HWc]  = v.w;
        }
    }
}

// ---------------- Fallback (R1): used only if ws too small ----------------
__global__ __launch_bounds__(256) void deform_unfold_k9(
    const float* __restrict__ x,
    const float* __restrict__ offset,
    float* __restrict__ out)
{
    constexpr int CPT = 8, NCG = Cc / CPT;
    int tid = blockIdx.x * blockDim.x + threadIdx.x;
    int sp   = tid & (HWc - 1);
    int rest = tid >> 14;
    int cg   = rest & (NCG - 1);
    int b    = rest >> 3;

    int wo = sp & (Wc - 1);
    int ho = sp >> 7;

    const float* offb = offset + (size_t)b * (2 * Kc) * HWc + sp;

    int   idx[Kc][4];
    float w[Kc][4];
#pragma unroll
    for (int k = 0; k < Kc; ++k) {
        float offy = offb[(size_t)(2 * k + 0) * HWc];
        float offx = offb[(size_t)(2 * k + 1) * HWc];
        float py = (float)(k / 3 + ho - 1) + offy;
        float px = (float)(k % 3 + wo - 1) + offx;
        float y0f = floorf(py), x0f = floorf(px);
        float ly = py - y0f, lx = px - x0f;
        float hy = 1.0f - ly, hx = 1.0f - lx;
        int y0 = (int)y0f, x0 = (int)x0f;
        int y1 = y0 + 1,   x1 = x0 + 1;
        bool vy0 = (unsigned)y0 < (unsigned)Hc;
        bool vy1 = (unsigned)y1 < (unsigned)Hc;
        bool vx0 = (unsigned)x0 < (unsigned)Wc;
        bool vx1 = (unsigned)x1 < (unsigned)Wc;
        w[k][0] = hy * hx * ((vy0 & vx0) ? 1.0f : 0.0f);
        w[k][1] = hy * lx * ((vy0 & vx1) ? 1.0f : 0.0f);
        w[k][2] = ly * hx * ((vy1 & vx0) ? 1.0f : 0.0f);
        w[k][3] = ly * lx * ((vy1 & vx1) ? 1.0f : 0.0f);
        int y0c = min(max(y0, 0), Hc - 1);
        int y1c = min(max(y1, 0), Hc - 1);
        int x0c = min(max(x0, 0), Wc - 1);
        int x1c = min(max(x1, 0), Wc - 1);
        idx[k][0] = (y0c << 7) + x0c;
        idx[k][1] = (y0c << 7) + x1c;
        idx[k][2] = (y1c << 7) + x0c;
        idx[k][3] = (y1c << 7) + x1c;
    }

    const float* xb = x + ((size_t)b * Cc + (size_t)cg * CPT) * HWc;
    float* ob = out + (((size_t)b * Cc + (size_t)cg * CPT) * Kc) * (size_t)HWc + sp;
#pragma unroll 1
    for (int c = 0; c < CPT; ++c) {
        const float* xp = xb + (size_t)c * HWc;
        float v[Kc];
#pragma unroll
        for (int k = 0; k < Kc; ++k)
            v[k] = w[k][0] * xp[idx[k][0]] + w[k][1] * xp[idx[k][1]]
                 + w[k][2] * xp[idx[k][2]] + w[k][3] * xp[idx[k][3]];
#pragma unroll
        for (int k = 0; k < Kc; ++k)
            ob[((size_t)c * Kc + k) * HWc] = v[k];
    }
}

extern "C" void kernel_launch(void* const* d_in, const int* in_sizes, int n_in,
                              void* d_out, int out_size, void* d_ws, size_t ws_size,
                              hipStream_t stream) {
    const float* x      = (const float*)d_in[0];
    const float* offset = (const float*)d_in[1];
    float* out          = (float*)d_out;

    const size_t ws_needed = (size_t)Bc * HWc * Cc * sizeof(float); // 33.5 MB

    if (ws_size >= ws_needed) {
        float* xT = (float*)d_ws;
        transpose_chw_hwc<<<Bc * 256, 256, 0, stream>>>(x, xT);
        deform_main<<<Bc * 256, 256, 0, stream>>>(xT, offset, out);
    } else {
        int total = Bc * (Cc / 8) * HWc;
        deform_unfold_k9<<<total / 256, 256, 0, stream>>>(x, offset, out);
    }
}

// Round 4
// 113.988 us; speedup vs baseline: 2.3094x; 2.3094x over previous
//
#include <hip/hip_runtime.h>

// DeformUnfold R3: LDS-staged scattered gathers.
// Block = (batch, output-row-pair, 32-channel half). Stage a 21-row window of
// one channel plane into LDS (double-buffered, coalesced float4), do the 36
// bilinear corner reads per sp as ds_read_b32. Sampling meta (4 LDS addrs +
// 4 weights per tap) is channel-independent -> registers, reused over 32 ch.
// Lanes whose clamped sample rows fall outside the window (|offset|>~8,
// P~1e-15) take a global-gather slow path with identical weights.

constexpr int Bc = 8;
constexpr int Cc = 64;
constexpr int Hc = 128;
constexpr int Wc = 128;
constexpr int Kc = 9;
constexpr int HWc = Hc * Wc;          // 16384
constexpr int ROWS = 21;              // staged window height
constexpr int TILE = ROWS * Wc;       // 2688 floats
constexpr int TILE4 = TILE / 4;       // 672 float4
constexpr int CPB = 32;               // channels per block
constexpr int MARG = 9;               // rows above r0 staged

__global__ __launch_bounds__(256, 4) void deform_lds(
    const float* __restrict__ x,
    const float* __restrict__ offset,
    float* __restrict__ out)
{
    __shared__ float buf[2][TILE];    // 2 x 10.5 KB

    // XCD swizzle: 1024 wgs, 8 XCDs -> each XCD owns one batch (4MB = L2)
    int wg = (int)((blockIdx.x & 7) * 128 + (blockIdx.x >> 3));
    int h  = wg & 1;                  // channel half
    int rp = (wg >> 1) & 63;          // row pair
    int b  = wg >> 7;

    int r0  = rp * 2;
    int w0  = min(max(r0 - MARG, 0), Hc - ROWS);   // window start row
    int tid = (int)threadIdx.x;
    int ho  = r0 + (tid >> 7);
    int wo  = tid & 127;
    int spg = r0 * Wc + tid;          // global spatial index (contig per wave)
    int ch0 = h * CPB;

    const float* offb = offset + (size_t)b * (2 * Kc) * HWc + spg;

    // ---- per-thread meta: channel-independent sampling data ----
    int   a00[Kc], a01[Kc], a10[Kc], a11[Kc];
    float w00[Kc], w01[Kc], w10[Kc], w11[Kc];
    bool allok = true;
#pragma unroll
    for (int k = 0; k < Kc; ++k) {
        float offy = offb[(size_t)(2 * k) * HWc];
        float offx = offb[(size_t)(2 * k + 1) * HWc];
        float py = (float)(k / 3 + ho - 1) + offy;
        float px = (float)(k % 3 + wo - 1) + offx;
        float y0f = floorf(py), x0f = floorf(px);
        float ly = py - y0f, lx = px - x0f;
        float hy = 1.0f - ly, hx = 1.0f - lx;
        int y0 = (int)y0f, x0v = (int)x0f;
        int y1 = y0 + 1,   x1 = x0v + 1;
        bool vy0 = (unsigned)y0  < (unsigned)Hc;
        bool vy1 = (unsigned)y1  < (unsigned)Hc;
        bool vx0 = (unsigned)x0v < (unsigned)Wc;
        bool vx1 = (unsigned)x1  < (unsigned)Wc;
        w00[k] = hy * hx * ((vy0 & vx0) ? 1.0f : 0.0f);
        w01[k] = hy * lx * ((vy0 & vx1) ? 1.0f : 0.0f);
        w10[k] = ly * hx * ((vy1 & vx0) ? 1.0f : 0.0f);
        w11[k] = ly * lx * ((vy1 & vx1) ? 1.0f : 0.0f);
        int y0c = min(max(y0, 0), Hc - 1);
        int y1c = min(max(y1, 0), Hc - 1);
        int x0c = min(max(x0v, 0), Wc - 1);
        int x1c = min(max(x1, 0), Wc - 1);
        allok = allok & (y0c >= w0) & (y0c < w0 + ROWS)
                      & (y1c >= w0) & (y1c < w0 + ROWS);
        int rl0 = (y0c - w0) * Wc;
        int rl1 = (y1c - w0) * Wc;
        a00[k] = rl0 + x0c;  a01[k] = rl0 + x1c;
        a10[k] = rl1 + x0c;  a11[k] = rl1 + x1c;
    }

    const float* xw = x + ((size_t)b * Cc + ch0) * HWc + (size_t)w0 * Wc;
    float* outb = out + (((size_t)b * Cc + ch0) * Kc) * (size_t)HWc + spg;
    const int wb = w0 * Wc;           // lds idx -> global idx bias (slow path)

    // ---- prologue: stage channel ch0 ----
    {
        const float4* src = (const float4*)xw;
        float4* dst = (float4*)buf[0];
#pragma unroll
        for (int j = 0; j < 3; ++j) {
            int i = tid + j * 256;
            if (i < TILE4) dst[i] = src[i];
        }
    }
    __syncthreads();

    float4 s0, s1, s2;
    for (int ci = 0; ci < CPB; ++ci) {
        const float* bcur = buf[ci & 1];
        // issue next channel's staging loads early (latency hides under compute)
        if (ci + 1 < CPB) {
            const float4* src = (const float4*)(xw + (size_t)(ci + 1) * HWc);
            s0 = src[tid];
            s1 = src[tid + 256];
            if (tid + 512 < TILE4) s2 = src[tid + 512];
        }
        float* oc = outb + (size_t)ci * (Kc * HWc);
        if (allok) {
#pragma unroll
            for (int k = 0; k < Kc; ++k) {
                float v = w00[k] * bcur[a00[k]] + w01[k] * bcur[a01[k]]
                        + w10[k] * bcur[a10[k]] + w11[k] * bcur[a11[k]];
                oc[(size_t)k * HWc] = v;
            }
        } else {
            // ultra-rare: clamped sample row outside staged window
            const float* xc = x + ((size_t)b * Cc + ch0 + ci) * HWc + wb;
#pragma unroll 1
            for (int k = 0; k < Kc; ++k) {
                float v = w00[k] * xc[a00[k]] + w01[k] * xc[a01[k]]
                        + w10[k] * xc[a10[k]] + w11[k] * xc[a11[k]];
                oc[(size_t)k * HWc] = v;
            }
        }
        __syncthreads();              // everyone done reading buf[ci&1]? no:
                                      // done reading buf[(ci)&1] this iter AND
                                      // buf[(ci+1)&1] was last read in ci-1
        if (ci + 1 < CPB) {
            float4* dst = (float4*)buf[(ci + 1) & 1];
            dst[tid]       = s0;
            dst[tid + 256] = s1;
            if (tid + 512 < TILE4) dst[tid + 512] = s2;
            __syncthreads();          // staged data visible before next compute
        }
    }
}

extern "C" void kernel_launch(void* const* d_in, const int* in_sizes, int n_in,
                              void* d_out, int out_size, void* d_ws, size_t ws_size,
                              hipStream_t stream) {
    const float* x      = (const float*)d_in[0];
    const float* offset = (const float*)d_in[1];
    float* out          = (float*)d_out;

    int grid = Bc * 64 * 2;           // 1024 blocks
    deform_lds<<<grid, 256, 0, stream>>>(x, offset, out);
}

// Round 5
// 104.370 us; speedup vs baseline: 2.5222x; 1.0922x over previous
//
#include <hip/hip_runtime.h>

// DeformUnfold R4: LDS-staged gathers + ds_read2 pair-reads + 4-row tiles.
// Block = (batch, 4-output-row quad, 32-channel half), 512 threads (1 sp each).
// Stage a 23-row window of one channel into LDS (double-buffered). Each tap's
// two x-corners are remapped to the adjacent pair (xb, xb+1), xb=clamp(x0,0,126),
// with branchless weight redistribution -> one ds_read2_b32 per row per tap.
// Rare lanes whose sample rows miss the window take a global slow path.

constexpr int Bc = 8;
constexpr int Cc = 64;
constexpr int Hc = 128;
constexpr int Wc = 128;
constexpr int Kc = 9;
constexpr int HWc = Hc * Wc;          // 16384
constexpr int ORc = 4;                // output rows per block
constexpr int ROWS = 23;              // staged window rows
constexpr int TILE = ROWS * Wc;       // 2944 floats (11.5 KB)
constexpr int TILE4 = TILE / 4;       // 736 float4
constexpr int CPB = 32;               // channels per block
constexpr int MARG = 9;               // rows staged above r0
constexpr int NT = 512;

__global__ __launch_bounds__(NT) void deform_lds2(
    const float* __restrict__ x,
    const float* __restrict__ offset,
    float* __restrict__ out)
{
    __shared__ float buf[2][TILE];    // 2 x 11.5 KB

    // XCD swizzle: 512 wgs / 8 XCDs -> each XCD owns one batch (4.2MB ~ L2)
    int wg = (int)((blockIdx.x & 7) * 64 + (blockIdx.x >> 3));
    int h  = wg & 1;                  // channel half
    int rq = (wg >> 1) & 31;          // row quad
    int b  = wg >> 6;

    int r0  = rq * ORc;
    int w0  = min(max(r0 - MARG, 0), Hc - ROWS);   // window start row
    int tid = (int)threadIdx.x;
    int ho  = r0 + (tid >> 7);
    int wo  = tid & 127;
    int spg = r0 * Wc + tid;          // global spatial index (contig per wave)
    int ch0 = h * CPB;

    const float* offb = offset + (size_t)b * (2 * Kc) * HWc + spg;

    // ---- per-thread meta: channel-independent sampling data ----
    int   at[Kc], ab[Kc];             // LDS dword idx of top/bottom pair base
    float wA[Kc], wB[Kc];             // column-pair weights
    float wyt[Kc], wyb[Kc];           // row weights (validity folded in)
    bool allok = true;
#pragma unroll
    for (int k = 0; k < Kc; ++k) {
        float offy = offb[(size_t)(2 * k) * HWc];
        float offx = offb[(size_t)(2 * k + 1) * HWc];
        float py = (float)(k / 3 + ho - 1) + offy;
        float px = (float)(k % 3 + wo - 1) + offx;
        float y0f = floorf(py), x0f = floorf(px);
        float ly = py - y0f, lx = px - x0f;
        float hy = 1.0f - ly, hx = 1.0f - lx;
        int y0 = (int)y0f, x0 = (int)x0f;
        int y1 = y0 + 1;

        bool vy0 = (unsigned)y0 < (unsigned)Hc;
        bool vy1 = (unsigned)y1 < (unsigned)Hc;
        wyt[k] = hy * (vy0 ? 1.0f : 0.0f);
        wyb[k] = ly * (vy1 ? 1.0f : 0.0f);

        // x-pair remap: always read (xb, xb+1); redistribute hx/lx weights.
        int xb = min(max(x0, 0), Wc - 2);
        bool n  = (x0 == xb);         // normal interior case
        bool lo = (x0 + 1 == xb);     // x0=-1: x1 lands on col 0
        bool hi = (x0 == xb + 1);     // x0=127: x0 lands on col 127
        wA[k] = (n ? hx : 0.0f) + (lo ? lx : 0.0f);
        wB[k] = (n ? lx : 0.0f) + (hi ? hx : 0.0f);

        int y0c = min(max(y0, 0), Hc - 1);
        int y1c = min(max(y1, 0), Hc - 1);
        allok = allok & (y0c >= w0) & (y0c < w0 + ROWS)
                      & (y1c >= w0) & (y1c < w0 + ROWS);
        at[k] = (y0c - w0) * Wc + xb;
        ab[k] = (y1c - w0) * Wc + xb;
    }

    const float* xw = x + ((size_t)b * Cc + ch0) * HWc + (size_t)w0 * Wc;
    float* outb = out + (((size_t)b * Cc + ch0) * Kc) * (size_t)HWc + spg;

    // ---- prologue: stage channel ch0 ----
    {
        const float4* src = (const float4*)xw;
        float4* dst = (float4*)buf[0];
        dst[tid] = src[tid];
        if (tid + NT < TILE4) dst[tid + NT] = src[tid + NT];
    }
    __syncthreads();

    float4 s0, s1;
    for (int ci = 0; ci < CPB; ++ci) {
        const float* bcur = buf[ci & 1];
        // issue next channel's staging loads early (hide under compute)
        if (ci + 1 < CPB) {
            const float4* src = (const float4*)(xw + (size_t)(ci + 1) * HWc);
            s0 = src[tid];
            if (tid + NT < TILE4) s1 = src[tid + NT];
        }
        float* oc = outb + (size_t)ci * (Kc * HWc);
        if (allok) {
#pragma unroll
            for (int k = 0; k < Kc; ++k) {
                const float* pt = &bcur[at[k]];
                const float* pb = &bcur[ab[k]];
                float t0 = pt[0], t1 = pt[1];      // -> ds_read2_b32
                float b0 = pb[0], b1 = pb[1];
                float v = wyt[k] * (wA[k] * t0 + wB[k] * t1)
                        + wyb[k] * (wA[k] * b0 + wB[k] * b1);
                oc[(size_t)k * HWc] = v;
            }
        } else {
            // ultra-rare: a clamped sample row fell outside the staged window
            const float* xc = x + ((size_t)b * Cc + ch0 + ci) * HWc + w0 * Wc;
#pragma unroll 1
            for (int k = 0; k < Kc; ++k) {
                float t0 = xc[at[k]], t1 = xc[at[k] + 1];
                float b0 = xc[ab[k]], b1 = xc[ab[k] + 1];
                float v = wyt[k] * (wA[k] * t0 + wB[k] * t1)
                        + wyb[k] * (wA[k] * b0 + wB[k] * b1);
                oc[(size_t)k * HWc] = v;
            }
        }
        __syncthreads();              // all reads of buf[ci&1] done
        if (ci + 1 < CPB) {
            float4* dst = (float4*)buf[(ci + 1) & 1];
            dst[tid] = s0;
            if (tid + NT < TILE4) dst[tid + NT] = s1;
            __syncthreads();          // staged data visible before next compute
        }
    }
}

extern "C" void kernel_launch(void* const* d_in, const int* in_sizes, int n_in,
                              void* d_out, int out_size, void* d_ws, size_t ws_size,
                              hipStream_t stream) {
    const float* x      = (const float*)d_in[0];
    const float* offset = (const float*)d_in[1];
    float* out          = (float*)d_out;

    int grid = Bc * (Hc / ORc) * (Cc / CPB);   // 8*32*2 = 512 blocks
    deform_lds2<<<grid, NT, 0, stream>>>(x, offset, out);
}

// Round 6
// 64.540 us; speedup vs baseline: 4.0788x; 1.6171x over previous
//
#include <hip/hip_runtime.h>

// DeformUnfold R5: 1-barrier software pipeline, 2 channels/iter, nt stores.
// Block = (batch, 4-row quad, 32-ch half), 512 threads, 1 sp each.
// Iter j: ds_write pair j+1 (regs loaded in iter j-1) -> buf[p^1],
//         issue loads pair j+2, compute pair j from buf[p], ONE barrier.
// Sampling meta (channel-independent) in registers; x-pair remap so each tap
// row is one ds_read2_b32. Rare out-of-window lanes take a global slow path.

constexpr int Bc = 8;
constexpr int Cc = 64;
constexpr int Hc = 128;
constexpr int Wc = 128;
constexpr int Kc = 9;
constexpr int HWc = 16384;
constexpr int ORc = 4;                // output rows per block
constexpr int ROWS = 23;              // staged window rows
constexpr int TILE = ROWS * Wc;       // 2944 floats
constexpr int TILE4 = TILE / 4;       // 736 float4
constexpr int CPB = 32;               // channels per block
constexpr int PAIRS = CPB / 2;        // 16 iterations
constexpr int MARG = 9;
constexpr int NT = 512;

__global__ __launch_bounds__(NT, 4) void deform_lds3(
    const float* __restrict__ x,
    const float* __restrict__ offset,
    float* __restrict__ out)
{
    __shared__ float buf[2][2][TILE];     // 46 KB: [phase][ch-of-pair][win]

    // XCD swizzle: batch b -> XCD b (x per batch ~4.2MB ~ one L2)
    int wg = (int)((blockIdx.x & 7) * 64 + (blockIdx.x >> 3));
    int h  = wg & 1;
    int rq = (wg >> 1) & 31;
    int b  = wg >> 6;

    int r0  = rq * ORc;
    int w0  = min(max(r0 - MARG, 0), Hc - ROWS);
    int tid = (int)threadIdx.x;
    int ho  = r0 + (tid >> 7);
    int wo  = tid & 127;
    int spg = r0 * Wc + tid;
    int ch0 = h * CPB;

    const float* offb = offset + (size_t)b * (2 * Kc) * HWc + spg;

    // ---- per-thread sampling meta (channel-independent) ----
    int   at[Kc], ab[Kc];
    float wA[Kc], wB[Kc], wyt[Kc], wyb[Kc];
    bool allok = true;
#pragma unroll
    for (int k = 0; k < Kc; ++k) {
        float offy = offb[(size_t)(2 * k) * HWc];
        float offx = offb[(size_t)(2 * k + 1) * HWc];
        float py = (float)(k / 3 + ho - 1) + offy;
        float px = (float)(k % 3 + wo - 1) + offx;
        float y0f = floorf(py), x0f = floorf(px);
        float ly = py - y0f, lx = px - x0f;
        float hy = 1.0f - ly, hx = 1.0f - lx;
        int y0 = (int)y0f, x0 = (int)x0f;
        int y1 = y0 + 1;

        bool vy0 = (unsigned)y0 < (unsigned)Hc;
        bool vy1 = (unsigned)y1 < (unsigned)Hc;
        wyt[k] = hy * (vy0 ? 1.0f : 0.0f);
        wyb[k] = ly * (vy1 ? 1.0f : 0.0f);

        int xb = min(max(x0, 0), Wc - 2);
        bool n  = (x0 == xb);
        bool lo = (x0 + 1 == xb);
        bool hi = (x0 == xb + 1);
        wA[k] = (n ? hx : 0.0f) + (lo ? lx : 0.0f);
        wB[k] = (n ? lx : 0.0f) + (hi ? hx : 0.0f);

        int y0c = min(max(y0, 0), Hc - 1);
        int y1c = min(max(y1, 0), Hc - 1);
        allok = allok & (y0c >= w0) & (y0c < w0 + ROWS)
                      & (y1c >= w0) & (y1c < w0 + ROWS);
        at[k] = (y0c - w0) * Wc + xb;
        ab[k] = (y1c - w0) * Wc + xb;
    }

    const float* xw = x + ((size_t)b * Cc + ch0) * HWc + (size_t)w0 * Wc;
    float* outb = out + (((size_t)b * Cc + ch0) * Kc) * (size_t)HWc + spg;

    // stage-pair helpers: pair p = channels (2p, 2p+1); 3 float4 per thread
    auto LOADP = [&](int p, float4& a0, float4& a1, float4& a2) {
        const float* s = xw + (size_t)(2 * p) * HWc;
        const float4* f0 = (const float4*)s;
        const float4* f1 = (const float4*)(s + HWc);
        a0 = f0[tid];                              // 0..511 -> plane0
        int i1 = tid + 512;                        // crosses plane boundary
        a1 = (i1 < TILE4) ? f0[i1] : f1[i1 - TILE4];
        int i2 = tid + 1024;                       // plane1 tail
        if (i2 < 2 * TILE4) a2 = f1[i2 - TILE4];
    };
    auto WRITEP = [&](int pb, float4 a0, float4 a1, float4 a2) {
        float4* d0 = (float4*)buf[pb][0];
        float4* d1 = (float4*)buf[pb][1];
        d0[tid] = a0;
        int i1 = tid + 512;
        if (i1 < TILE4) d0[i1] = a1; else d1[i1 - TILE4] = a1;
        int i2 = tid + 1024;
        if (i2 < 2 * TILE4) d1[i2 - TILE4] = a2;
    };
    auto COMPUTE = [&](int pb, int p) {
        const float* B0 = buf[pb][0];
        const float* B1 = buf[pb][1];
        float* oc0 = outb + (size_t)(2 * p) * (Kc * HWc);
        float* oc1 = oc0 + (size_t)Kc * HWc;
        if (allok) {
#pragma unroll
            for (int k = 0; k < Kc; ++k) {
                float t00 = B0[at[k]], t01 = B0[at[k] + 1];   // ds_read2
                float u00 = B0[ab[k]], u01 = B0[ab[k] + 1];
                float t10 = B1[at[k]], t11 = B1[at[k] + 1];
                float u10 = B1[ab[k]], u11 = B1[ab[k] + 1];
                float v0 = wyt[k] * (wA[k] * t00 + wB[k] * t01)
                         + wyb[k] * (wA[k] * u00 + wB[k] * u01);
                float v1 = wyt[k] * (wA[k] * t10 + wB[k] * t11)
                         + wyb[k] * (wA[k] * u10 + wB[k] * u11);
                __builtin_nontemporal_store(v0, &oc0[(size_t)k * HWc]);
                __builtin_nontemporal_store(v1, &oc1[(size_t)k * HWc]);
            }
        } else {
            // ultra-rare: clamped sample row outside staged window
            const float* xc0 = x + ((size_t)b * Cc + ch0 + 2 * p) * HWc + w0 * Wc;
            const float* xc1 = xc0 + HWc;
#pragma unroll 1
            for (int k = 0; k < Kc; ++k) {
                float t00 = xc0[at[k]], t01 = xc0[at[k] + 1];
                float u00 = xc0[ab[k]], u01 = xc0[ab[k] + 1];
                float t10 = xc1[at[k]], t11 = xc1[at[k] + 1];
                float u10 = xc1[ab[k]], u11 = xc1[ab[k] + 1];
                float v0 = wyt[k] * (wA[k] * t00 + wB[k] * t01)
                         + wyb[k] * (wA[k] * u00 + wB[k] * u01);
                float v1 = wyt[k] * (wA[k] * t10 + wB[k] * t11)
                         + wyb[k] * (wA[k] * u10 + wB[k] * u11);
                oc0[(size_t)k * HWc] = v0;
                oc1[(size_t)k * HWc] = v1;
            }
        }
    };

    // ---- prologue: stage pair 0, preload pair 1 ----
    float4 a0, a1, a2, n0, n1, n2;
    LOADP(0, a0, a1, a2);
    WRITEP(0, a0, a1, a2);
    LOADP(1, n0, n1, n2);
    __syncthreads();

    // ---- main pipeline: ONE barrier per pair ----
    for (int j = 0; j < PAIRS; ++j) {
        int pb = j & 1;
        if (j + 1 < PAIRS) WRITEP(pb ^ 1, n0, n1, n2);  // pair j+1 -> other buf
        if (j + 2 < PAIRS) LOADP(j + 2, a0, a1, a2);    // issue pair j+2
        COMPUTE(pb, j);
        __syncthreads();
        n0 = a0; n1 = a1; n2 = a2;
    }
}

extern "C" void kernel_launch(void* const* d_in, const int* in_sizes, int n_in,
                              void* d_out, int out_size, void* d_ws, size_t ws_size,
                              hipStream_t stream) {
    const float* x      = (const float*)d_in[0];
    const float* offset = (const float*)d_in[1];
    float* out          = (float*)d_out;

    int grid = Bc * (Hc / ORc) * (Cc / CPB);   // 512 blocks
    deform_lds3<<<grid, NT, 0, stream>>>(x, offset, out);
}